// Round 2
// baseline (753.682 us; speedup 1.0000x reference)
//
#include <hip/hip_runtime.h>
#include <math.h>

// Problem constants
#define Bsz 64
#define Tsz 4096
#define Dsz 512
#define SLICES 8                 // T-slices (blocks per batch)
#define CH 16                    // rows per chunk
#define ITERS (Tsz / SLICES / CH) // 32 chunks per block (512 rows)
#define THREADS 512              // 8 waves

// Persistent phase 1: grid (8,64) = 512 blocks = exactly 2 blocks/CU.
// Each block owns a contiguous 512-row span of x[b] (1 MiB stream), processed
// as 32 chunks of 16 rows with double-buffered LDS (2 x 32 KiB) + register
// prefetch: chunk c+1's global loads issue at the top of iteration c and are
// only consumed (ds_write) at the bottom, so they fly during compute.
// Per-thread accumulators live in registers across all chunks; one atomicAdd
// per thread at the end (16x fewer atomics than one-block-per-chunk).
// softmax needs no max-subtraction: e = tanh(..) in [-1,1].
__global__ __launch_bounds__(THREADS, 4) void attn_phase1(
    const float* __restrict__ x, const float* __restrict__ W,
    const float* __restrict__ bias, float* __restrict__ num,
    float* __restrict__ den) {
  __shared__ float xs[2][CH * Dsz];   // 2 x 32 KiB
  __shared__ float wts[2][CH];        // per-chunk softmax weights (double-buffered)

  const int tid  = threadIdx.x;
  const int lane = tid & 63;
  const int wave = tid >> 6;
  const int sb = blockIdx.x;          // slice
  const int b  = blockIdx.y;          // batch
  const int row0 = sb * (Tsz / SLICES);

  const float* src = x + ((size_t)b * Tsz + row0) * Dsz;

  // W fragment: lane covers cols {lane + 64k}
  float Wreg[8];
#pragma unroll
  for (int k = 0; k < 8; ++k) Wreg[k] = W[lane + 64 * k];

  // Prologue: chunk 0 -> regs -> buf0
  float4 pf[4];
  {
    const float4* s4 = (const float4*)src;
#pragma unroll
    for (int i = 0; i < 4; ++i) pf[i] = s4[i * THREADS + tid];
    float4* l4 = (float4*)xs[0];
#pragma unroll
    for (int i = 0; i < 4; ++i) l4[i * THREADS + tid] = pf[i];
  }
  __syncthreads();

  float acc = 0.f;       // column-tid weighted sum
  float den_acc = 0.f;   // valid on wave0

  for (int c = 0; c < ITERS; ++c) {
    const int cur = c & 1, nxt = cur ^ 1;
    const bool more = (c + 1 < ITERS);

    // Issue next chunk's global loads (consumed at ds_write below)
    if (more) {
      const float4* n4 = (const float4*)(src + (size_t)(c + 1) * CH * Dsz);
#pragma unroll
      for (int i = 0; i < 4; ++i) pf[i] = n4[i * THREADS + tid];
    }

    // Row dots: 8 waves x 2 rows, butterfly reduce
#pragma unroll
    for (int q = 0; q < 2; ++q) {
      const int r = wave + 8 * q;
      const float* xr = xs[cur] + r * Dsz;
      float p = 0.f;
#pragma unroll
      for (int k = 0; k < 8; ++k) p += xr[lane + 64 * k] * Wreg[k];
#pragma unroll
      for (int off = 32; off >= 1; off >>= 1) p += __shfl_xor(p, off, 64);
      if (lane == 0) wts[cur][r] = expf(tanhf(p + bias[row0 + c * CH + r]));
    }
    __syncthreads();  // wts[cur] visible; prior-iter readers of buf[nxt] done

    // Weighted column sums (conflict-free: consecutive lanes -> consecutive words)
#pragma unroll
    for (int t = 0; t < CH; ++t) acc += wts[cur][t] * xs[cur][t * Dsz + tid];

    // den partial: wave0 reduces the 16 weights
    if (wave == 0) {
      float dv = (lane < CH) ? wts[cur][lane] : 0.f;
#pragma unroll
      for (int off = 8; off >= 1; off >>= 1) dv += __shfl_xor(dv, off, 64);
      den_acc += dv;
    }

    // Stage prefetched chunk into the other buffer
    if (more) {
      float4* n4l = (float4*)xs[nxt];
#pragma unroll
      for (int i = 0; i < 4; ++i) n4l[i * THREADS + tid] = pf[i];
    }
    __syncthreads();  // buf[nxt] ready for next iteration
  }

  atomicAdd(&num[(size_t)b * Dsz + tid], acc);
  if (wave == 0 && lane == 0) atomicAdd(&den[b], den_acc);
}

// Phase 2: out[b,d] = num[b,d] / den[b]
__global__ __launch_bounds__(512) void attn_phase2(
    const float* __restrict__ num, const float* __restrict__ den,
    float* __restrict__ out) {
  const int i = blockIdx.x * blockDim.x + threadIdx.x;  // 0..32767
  const int b = i >> 9;
  out[i] = num[i] / den[b];
}

extern "C" void kernel_launch(void* const* d_in, const int* in_sizes, int n_in,
                              void* d_out, int out_size, void* d_ws, size_t ws_size,
                              hipStream_t stream) {
  const float* x    = (const float*)d_in[0];  // [B,T,D]
  const float* W    = (const float*)d_in[1];  // [D,1]
  const float* bias = (const float*)d_in[2];  // [T,1]
  float* num = (float*)d_ws;                  // [B*D]
  float* den = num + (size_t)Bsz * Dsz;       // [B]

  // ws is poisoned 0xAA before every launch -> zero the accumulators
  hipMemsetAsync(d_ws, 0, ((size_t)Bsz * Dsz + Bsz) * sizeof(float), stream);

  dim3 g1(SLICES, Bsz);
  attn_phase1<<<g1, THREADS, 0, stream>>>(x, W, bias, num, den);
  attn_phase2<<<Bsz, Dsz, 0, stream>>>(num, den, (float*)d_out);
}